// Round 4
// baseline (153.844 us; speedup 1.0000x reference)
//
#include <hip/hip_runtime.h>

// Problem constants (from reference)
#define DIM     1024
#define N_CLS   10
#define NROWS   16384
#define IMG     784

// Only columns [0, 784) of ref are nonzero -> only those z columns matter.
// 32-lane groups: sublane s owns f32x4 column s+32j. 196 f32x4 = 6 full
// steps + one half-masked step (s<16). LDS ref zero-padded to 224 so the
// masked step's ds_read addresses stay valid; math stays EXACT.
#define NF4      196   // float4 per row actually used (784/4)
#define NF4_PAD  224   // 7*32 (zero tail)
#define NSTEP    7
#define LSTRIDE  224   // f32x4 stride per class in LDS (35840 B total)

// 512-thread blocks, 8 waves, 2 rows/wave (one per 32-lane group) -> 16
// rows/block, 1024 blocks = 4 blocks/CU (LDS 4x35KB=140KB <= 160KB), i.e.
// 32 waves/CU = 8 waves/SIMD -- requires VGPR <= 64, which the compiler
// already targeted voluntarily in the last two rounds (VGPR_Count=64).
#define WAVES_PER_BLK 8
#define ROWS_PER_BLK  16

typedef float f32x4 __attribute__((ext_vector_type(4)));
typedef float f32x2 __attribute__((ext_vector_type(2)));

static __device__ __forceinline__ f32x2 lo2(f32x4 v) {
  return __builtin_shufflevector(v, v, 0, 1);
}
static __device__ __forceinline__ f32x2 hi2(f32x4 v) {
  return __builtin_shufflevector(v, v, 2, 3);
}

// Packed dual-FP32 FMA (the 157 TF path); compiler won't form it from scalar.
static __device__ __forceinline__ void pk_fma(f32x2& acc, f32x2 a, f32x2 b) {
  asm("v_pk_fma_f32 %0, %1, %2, %0" : "+v"(acc) : "v"(a), "v"(b));
}

// ---------------------------------------------------------------------------
// DPP reductions. bound_ctrl=1: masked/invalid lanes contribute 0.
// ---------------------------------------------------------------------------
#define DPP_ADD(ctrl, rmask, bmask)                                           \
  x += __int_as_float(__builtin_amdgcn_update_dpp(                            \
      0, __float_as_int(x), ctrl, rmask, bmask, true));

// Full-wave sum; result valid in lane 63 (canon normalization only).
__device__ __forceinline__ float wave64_sum(float x) {
  DPP_ADD(0x111, 0xf, 0xf)  // row_shr:1
  DPP_ADD(0x112, 0xf, 0xf)  // row_shr:2
  DPP_ADD(0x114, 0xf, 0xe)  // row_shr:4
  DPP_ADD(0x118, 0xf, 0xc)  // row_shr:8
  DPP_ADD(0x142, 0xa, 0xf)  // row_bcast:15
  DPP_ADD(0x143, 0xc, 0xf)  // row_bcast:31
  return x;
}

// 32-lane group sum; results valid in lanes 31 and 63 (s==31 of each group).
__device__ __forceinline__ float group32_sum(float x) {
  DPP_ADD(0x111, 0xf, 0xf)  // row_shr:1
  DPP_ADD(0x112, 0xf, 0xf)  // row_shr:2
  DPP_ADD(0x114, 0xf, 0xe)  // row_shr:4
  DPP_ADD(0x118, 0xf, 0xc)  // row_shr:8  -> lane15 of each DPP-row = row sum
  DPP_ADD(0x142, 0xa, 0xf)  // row_bcast:15 -> lanes 31/63 = 32-lane sums
  return x;
}
#undef DPP_ADD

// ---------------------------------------------------------------------------
// Single fused kernel: stage canon -> LDS (zero-padded), normalize in LDS,
// then swap-test 16 rows per block. Lane (g,s): group g in {0,1} owns row
// row0+g, sublane s in [0,32) owns f32x4 column s+32j. All ds_reads share
// one base vaddr + imm offsets (max 35328 < 64 KiB).
// ---------------------------------------------------------------------------
__global__ __launch_bounds__(512, 8) void swaptest_kernel(
    const float* __restrict__ zre, const float* __restrict__ zim,
    const float* __restrict__ canon, float* __restrict__ out) {
  __shared__ f32x4 lref[N_CLS * LSTRIDE];  // 35840 B -> 4 blocks/CU

  const int t = threadIdx.x;
  const int lane = t & 63;
  const int wave = t >> 6;

  // ---- stage canon (zero-padding cols >= 784) ----
#pragma unroll
  for (int c = 0; c < N_CLS; ++c) {
    if (t < NF4_PAD) {
      f32x4 v = {0.f, 0.f, 0.f, 0.f};
      if (t < NF4) v = ((const f32x4*)canon)[c * NF4 + t];
      lref[c * LSTRIDE + t] = v;
    }
  }
  __syncthreads();

  // ---- normalize each class in LDS (wave w: classes w, w+8) ----
  for (int c = wave; c < N_CLS; c += WAVES_PER_BLK) {
    float ss = 0.f;
    for (int i = lane; i < NF4_PAD; i += 64) {
      f32x4 v = lref[c * LSTRIDE + i];
      ss += v.x * v.x + v.y * v.y + v.z * v.z + v.w * v.w;
    }
    ss = wave64_sum(ss);                       // lane 63
    float inv = __shfl(1.0f / sqrtf(ss), 63);  // broadcast
    for (int i = lane; i < NF4_PAD; i += 64) {
      f32x4 v = lref[c * LSTRIDE + i];
      v.x *= inv; v.y *= inv; v.z *= inv; v.w *= inv;
      lref[c * LSTRIDE + i] = v;
    }
  }
  __syncthreads();

  // ---- swap test ----
  const int s = lane & 31;
  const int g = lane >> 5;
  const int row = blockIdx.x * ROWS_PER_BLK + wave * 2 + g;

  const f32x4* pr = (const f32x4*)(zre + ((size_t)row << 10)) + s;
  const f32x4* pi = (const f32x4*)(zim + ((size_t)row << 10)) + s;

  f32x2 accr[N_CLS], acci[N_CLS];
#pragma unroll
  for (int c = 0; c < N_CLS; ++c) {
    accr[c] = (f32x2){0.f, 0.f};
    acci[c] = (f32x2){0.f, 0.f};
  }

#pragma unroll
  for (int j = 0; j < NSTEP; ++j) {
    f32x4 zr = {0.f, 0.f, 0.f, 0.f};
    f32x4 zi = {0.f, 0.f, 0.f, 0.f};
    // Last step covers f32x4 indices 192..207 with sublanes s<16 only;
    // other lanes keep exact zeros (ref is zero there anyway).
    if (j < NSTEP - 1 || s < 16) {
      zr = pr[j * 32];  // byte offset j*512, imm-foldable
      zi = pi[j * 32];
    }
#pragma unroll
    for (int c = 0; c < N_CLS; ++c) {
      // 2-way broadcast across groups (same address) -> conflict-free.
      const f32x4 rv = lref[c * LSTRIDE + j * 32 + s];
      pk_fma(accr[c], lo2(zr), lo2(rv));
      pk_fma(accr[c], hi2(zr), hi2(rv));
      pk_fma(acci[c], lo2(zi), lo2(rv));
      pk_fma(acci[c], hi2(zi), hi2(rv));
    }
  }

  // 32-lane reductions; totals land in lane 31 of each group (s==31).
#pragma unroll
  for (int c = 0; c < N_CLS; ++c) {
    float sr = group32_sum(accr[c].x + accr[c].y);
    float si = group32_sum(acci[c].x + acci[c].y);
    if (s == 31) {
      out[(size_t)row * N_CLS + c] = sr * sr + si * si;
    }
  }
}

// ---------------------------------------------------------------------------
extern "C" void kernel_launch(void* const* d_in, const int* in_sizes, int n_in,
                              void* d_out, int out_size, void* d_ws,
                              size_t ws_size, hipStream_t stream) {
  const float* z_re = (const float*)d_in[0];
  const float* z_im = (const float*)d_in[1];
  const float* canon = (const float*)d_in[2];
  float* out = (float*)d_out;
  (void)d_ws; (void)ws_size;

  const int nblk = NROWS / ROWS_PER_BLK;  // 1024 blocks, 4/CU, one round
  swaptest_kernel<<<nblk, 512, 0, stream>>>(z_re, z_im, canon, out);
}

// Round 5
// 151.981 us; speedup vs baseline: 1.0123x; 1.0123x over previous
//
#include <hip/hip_runtime.h>

// Problem constants (from reference)
#define DIM     1024
#define N_CLS   10
#define NROWS   16384
#define IMG     784

// Only columns [0,784) of ref are nonzero. A wave covers a row in 4 chunks of
// 64 f32x4; chunk 3 (cols 768..1023) is masked to lanes<16 (cols 768..831),
// saving 18.6% of z traffic exactly (ref is zero beyond col 783).
#define NF4       196  // used f32x4 per row (784/4)
#define NCHUNK    4
#define LSTRIDE   256  // f32x4 per class in LDS, zero-padded (full chunk reads)

#define WAVES_PER_BLK 4
#define ROWS_PER_WAVE 8
// grid = 16384 / (4*8) = 512 blocks -> 2 blocks/CU, 8 waves/CU (VGPR-bound).

typedef float f32x4 __attribute__((ext_vector_type(4)));
typedef float f32x2 __attribute__((ext_vector_type(2)));

static __device__ __forceinline__ f32x2 lo2(f32x4 v) {
  return __builtin_shufflevector(v, v, 0, 1);
}
static __device__ __forceinline__ f32x2 hi2(f32x4 v) {
  return __builtin_shufflevector(v, v, 2, 3);
}

// Packed dual-FP32 FMA; compiler won't form it from scalar code.
static __device__ __forceinline__ void pk_fma(f32x2& acc, f32x2 a, f32x2 b) {
  asm("v_pk_fma_f32 %0, %1, %2, %0" : "+v"(acc) : "v"(a), "v"(b));
}

// ---------------------------------------------------------------------------
// Wave64 DPP sum; result valid in lane 63. bound_ctrl=1: masked lanes add 0.
// ---------------------------------------------------------------------------
__device__ __forceinline__ float wave64_sum(float x) {
#define DPP_ADD(ctrl, rmask, bmask)                                           \
  x += __int_as_float(__builtin_amdgcn_update_dpp(                            \
      0, __float_as_int(x), ctrl, rmask, bmask, true));
  DPP_ADD(0x111, 0xf, 0xf)  // row_shr:1
  DPP_ADD(0x112, 0xf, 0xf)  // row_shr:2
  DPP_ADD(0x114, 0xf, 0xe)  // row_shr:4
  DPP_ADD(0x118, 0xf, 0xc)  // row_shr:8
  DPP_ADD(0x142, 0xa, 0xf)  // row_bcast:15
  DPP_ADD(0x143, 0xc, 0xf)  // row_bcast:31
#undef DPP_ADD
  return x;
}

// ---------------------------------------------------------------------------
// Fused kernel. Prologue (LDS): stage canon zero-padded, normalize, then each
// wave pulls its ref fragment into VGPRs (refv[4][10], 160 regs). Main loop
// has NO LDS reads: per row, 4 chunk-steps of {consume z regs, refill same
// regs with next row's chunk, 40 pk_fma}. Loads issue continuously across
// rows -> counted vmcnt, memory pipe never drains.
// ---------------------------------------------------------------------------
__global__ __launch_bounds__(256, 2) void swaptest_kernel(
    const float* __restrict__ zre, const float* __restrict__ zim,
    const float* __restrict__ canon, float* __restrict__ out) {
  __shared__ f32x4 lref[N_CLS * LSTRIDE];  // 40 KiB -> 2 blocks/CU fits

  const int t = threadIdx.x;
  const int lane = t & 63;
  const int wave = t >> 6;

  // ---- stage canon -> LDS, zero-padding f32x4 idx >= 196 ----
#pragma unroll
  for (int c = 0; c < N_CLS; ++c) {
    f32x4 v = {0.f, 0.f, 0.f, 0.f};
    if (t < NF4) v = ((const f32x4*)canon)[c * NF4 + t];
    lref[c * LSTRIDE + t] = v;
  }
  __syncthreads();

  // ---- normalize each class in LDS (wave w: classes w, w+4, w+8) ----
  for (int c = wave; c < N_CLS; c += WAVES_PER_BLK) {
    float ss = 0.f;
#pragma unroll
    for (int j = 0; j < LSTRIDE / 64; ++j) {
      f32x4 v = lref[c * LSTRIDE + j * 64 + lane];
      ss += v.x * v.x + v.y * v.y + v.z * v.z + v.w * v.w;
    }
    ss = wave64_sum(ss);                       // lane 63
    float inv = __shfl(1.0f / sqrtf(ss), 63);  // broadcast
#pragma unroll
    for (int j = 0; j < LSTRIDE / 64; ++j) {
      f32x4 v = lref[c * LSTRIDE + j * 64 + lane];
      v.x *= inv; v.y *= inv; v.z *= inv; v.w *= inv;
      lref[c * LSTRIDE + j * 64 + lane] = v;
    }
  }
  __syncthreads();

  // ---- pull ref fragment into registers (one-time, amortized over 8 rows) --
  f32x4 refv[NCHUNK][N_CLS];
#pragma unroll
  for (int k = 0; k < NCHUNK; ++k) {
#pragma unroll
    for (int c = 0; c < N_CLS; ++c) {
      refv[k][c] = lref[c * LSTRIDE + k * 64 + lane];
    }
  }

  // ---- swap test: 8 rows per wave, rolling z prefetch ----
  const int wrow0 = (blockIdx.x * WAVES_PER_BLK + wave) * ROWS_PER_WAVE;
  const f32x4* pr = (const f32x4*)zre + ((size_t)wrow0 << 8) + lane;
  const f32x4* pi = (const f32x4*)zim + ((size_t)wrow0 << 8) + lane;
  const bool tail = (lane < 16);  // chunk 3: only cols 768..831 are needed

  f32x4 bzr[NCHUNK], bzi[NCHUNK];
#pragma unroll
  for (int k = 0; k < NCHUNK; ++k) {
    bzr[k] = (f32x4){0.f, 0.f, 0.f, 0.f};
    bzi[k] = (f32x4){0.f, 0.f, 0.f, 0.f};
    if (k < NCHUNK - 1 || tail) {
      bzr[k] = pr[k * 64];
      bzi[k] = pi[k * 64];
    }
  }

#pragma unroll
  for (int r = 0; r < ROWS_PER_WAVE; ++r) {
    f32x2 accr[N_CLS], acci[N_CLS];
#pragma unroll
    for (int c = 0; c < N_CLS; ++c) {
      accr[c] = (f32x2){0.f, 0.f};
      acci[c] = (f32x2){0.f, 0.f};
    }

#pragma unroll
    for (int k = 0; k < NCHUNK; ++k) {
      const f32x4 zr = bzr[k];
      const f32x4 zi = bzi[k];
      // Refill this slot with NEXT row's chunk k: full row of compute + the
      // reduction phase covers the latency; masked lanes keep exact zeros.
      if (r + 1 < ROWS_PER_WAVE && (k < NCHUNK - 1 || tail)) {
        bzr[k] = pr[(size_t)(r + 1) * 256 + k * 64];
        bzi[k] = pi[(size_t)(r + 1) * 256 + k * 64];
      }
#pragma unroll
      for (int c = 0; c < N_CLS; ++c) {
        const f32x4 rv = refv[k][c];
        pk_fma(accr[c], lo2(zr), lo2(rv));
        pk_fma(accr[c], hi2(zr), hi2(rv));
        pk_fma(acci[c], lo2(zi), lo2(rv));
        pk_fma(acci[c], hi2(zi), hi2(rv));
      }
    }

    const int row = wrow0 + r;
#pragma unroll
    for (int c = 0; c < N_CLS; ++c) {
      float sr = wave64_sum(accr[c].x + accr[c].y);
      float si = wave64_sum(acci[c].x + acci[c].y);
      if (lane == 63) {
        out[(size_t)row * N_CLS + c] = sr * sr + si * si;
      }
    }
  }
}

// ---------------------------------------------------------------------------
extern "C" void kernel_launch(void* const* d_in, const int* in_sizes, int n_in,
                              void* d_out, int out_size, void* d_ws,
                              size_t ws_size, hipStream_t stream) {
  const float* z_re = (const float*)d_in[0];
  const float* z_im = (const float*)d_in[1];
  const float* canon = (const float*)d_in[2];
  float* out = (float*)d_out;
  (void)d_ws; (void)ws_size;

  const int nblk = NROWS / (WAVES_PER_BLK * ROWS_PER_WAVE);  // 512
  swaptest_kernel<<<nblk, 64 * WAVES_PER_BLK, 0, stream>>>(z_re, z_im, canon,
                                                           out);
}